// Round 1
// baseline (8724.389 us; speedup 1.0000x reference)
//
#include <hip/hip_runtime.h>

#define H 512
#define MTILE 64
#define NBLK 8192
#define STEPC (2.4f / 63.0f)

typedef _Float16 half8 __attribute__((ext_vector_type(8)));
typedef float floatx4 __attribute__((ext_vector_type(4)));

__device__ inline float silu_f(float x) { return x / (1.0f + __expf(-x)); }

typedef const __attribute__((address_space(1))) unsigned int* gp_t;
typedef __attribute__((address_space(3))) unsigned int* lp_t;

__device__ inline void async16(const _Float16* g, _Float16* l) {
    __builtin_amdgcn_global_load_lds((gp_t)g, (lp_t)l, 16, 0, 0);
}

// ---- prep 1: lat_part[b][j] = b0[j] + sum_d lat[b][d] * W0[d][j] ----
__global__ void prep_latw(const float* __restrict__ lat, const float* __restrict__ W0,
                          const float* __restrict__ b0, float* __restrict__ latw) {
    __shared__ float sl[H];
    const int b = blockIdx.x;
    const int j = threadIdx.x;
    sl[j] = lat[b * H + j];
    __syncthreads();
    float acc = b0[j];
#pragma unroll 8
    for (int d = 0; d < H; ++d) acc += sl[d] * W0[d * H + j];
    latw[b * H + j] = acc;
}

// ---- prep 2: split W1/W2 into fp16 hi/lo, slab-major layout ----
// layout: [(l*32 + s)][part][nl<256][kk<32]  (slab s = nh*16 + kc)
__global__ void prep_wsplit(const float* __restrict__ W1, const float* __restrict__ W2,
                            _Float16* __restrict__ ws) {
    const int id = blockIdx.x * 512 + threadIdx.x;   // 0 .. 524287
    const int l = id >> 18;
    const int rem = id & 0x3FFFF;                    // k*512 + n
    const int k = rem >> 9, n = rem & 511;
    const float w = (l == 0 ? W1 : W2)[rem];
    const _Float16 hi = (_Float16)w;
    const _Float16 lo = (_Float16)(w - (float)hi);
    const int s = (n >> 8) * 16 + (k >> 5);
    const int nl = n & 255, kk = k & 31;
    const size_t base = (((size_t)(l * 32 + s) * 2 + 0) * 256 + nl) * 32 + kk;
    ws[base] = hi;
    ws[base + 8192] = lo;                            // part stride = 256*32
}

// ---- main fused kernel ----
__global__ __launch_bounds__(512, 2) void mesh_main(
    const float* __restrict__ W0, const float* __restrict__ b1,
    const float* __restrict__ b2, const float* __restrict__ W3,
    const float* __restrict__ b3, const float* __restrict__ latw,
    const _Float16* __restrict__ wsplit, float* __restrict__ out) {

    __shared__ _Float16 hbuf[MTILE][H];          // 64 KB, [m][k]
    __shared__ _Float16 wbuf[2][2][256][32];     // 64 KB, [dbuf][part][n][kk]
    __shared__ float partials[8][MTILE];         // 2 KB

    const int tid = threadIdx.x;
    const int wave = tid >> 6, lane = tid & 63;
    const int quad = lane >> 4, t = lane & 15;
    const int bi = blockIdx.x;
    const int b = bi >> 12;
    const int p0 = (bi & 4095) << 6;
    const float c0 = -1.2f + (float)(p0 >> 12) * STEPC;
    const float c1 = -1.2f + (float)((p0 >> 6) & 63) * STEPC;

    // ---- layer 0: h0 = silu(lat_part + coords@W0c + b0), fp32 VALU ----
    {
        const int j = tid;
        const float lw = latw[b * H + j];
        const float w0 = W0[(H + 0) * H + j];
        const float w1 = W0[(H + 1) * H + j];
        const float w2 = W0[(H + 2) * H + j];
#pragma unroll 4
        for (int m = 0; m < MTILE; ++m) {
            const float c2 = -1.2f + (float)m * STEPC;
            const float x = lw + c0 * w0 + c1 * w1 + c2 * w2;
            hbuf[m][j] = (_Float16)silu_f(x);
        }
    }

    // per-lane column constants: col(nh,nt) = nh*256 + wave*32 + nt*16 + t
    float b1v[2][2], b2v[2][2], w3v[2][2];
#pragma unroll
    for (int nh = 0; nh < 2; ++nh)
#pragma unroll
        for (int nt = 0; nt < 2; ++nt) {
            const int col = nh * 256 + wave * 32 + nt * 16 + t;
            b1v[nh][nt] = b1[col];
            b2v[nh][nt] = b2[col];
            w3v[nh][nt] = W3[col];
        }

    floatx4 acc[2][4][2];

    auto zero_acc = [&]() {
#pragma unroll
        for (int nh = 0; nh < 2; ++nh)
#pragma unroll
            for (int mf = 0; mf < 4; ++mf)
#pragma unroll
                for (int nt = 0; nt < 2; ++nt) {
                    acc[nh][mf][nt][0] = 0.f; acc[nh][mf][nt][1] = 0.f;
                    acc[nh][mf][nt][2] = 0.f; acc[nh][mf][nt][3] = 0.f;
                }
    };

    auto stage_slab = [&](int l, int s, int buf) {
        const _Float16* src = wsplit + ((size_t)(l * 32 + s) * 16384);
        _Float16* dst = &wbuf[buf][0][0][0];
#pragma unroll
        for (int r = 0; r < 4; ++r)
            async16(src + r * 4096 + tid * 8, dst + r * 4096 + tid * 8);
    };

    auto compute_slab = [&](int s) {
        const int nh = s >> 4, kc = s & 15;
        const int buf = s & 1;
        half8 a[4];
#pragma unroll
        for (int mf = 0; mf < 4; ++mf)
            a[mf] = *(const half8*)&hbuf[mf * 16 + t][kc * 32 + quad * 8];
#pragma unroll
        for (int nt = 0; nt < 2; ++nt) {
            const half8 bh = *(const half8*)&wbuf[buf][0][wave * 32 + nt * 16 + t][quad * 8];
            const half8 bl = *(const half8*)&wbuf[buf][1][wave * 32 + nt * 16 + t][quad * 8];
#pragma unroll
            for (int mf = 0; mf < 4; ++mf) {
                acc[nh][mf][nt] =
                    __builtin_amdgcn_mfma_f32_16x16x32_f16(a[mf], bh, acc[nh][mf][nt], 0, 0, 0);
                acc[nh][mf][nt] =
                    __builtin_amdgcn_mfma_f32_16x16x32_f16(a[mf], bl, acc[nh][mf][nt], 0, 0, 0);
            }
        }
    };

    auto run_gemm = [&](int l) {
        __syncthreads();              // hbuf ready; prev wbuf readers done
        stage_slab(l, 0, 0);
#pragma unroll 1
        for (int s = 0; s < 32; ++s) {
            __syncthreads();          // slab s resident; buf (s+1)&1 free
            if (s < 31) stage_slab(l, s + 1, (s + 1) & 1);
            compute_slab(s);
        }
        __syncthreads();              // all hbuf/wbuf reads retired
    };

    // ---- GEMM 1 ----
    zero_acc();
    run_gemm(0);
    // writeback h1 = silu(acc + b1)
#pragma unroll
    for (int nh = 0; nh < 2; ++nh)
#pragma unroll
        for (int mf = 0; mf < 4; ++mf)
#pragma unroll
            for (int nt = 0; nt < 2; ++nt)
#pragma unroll
                for (int r = 0; r < 4; ++r) {
                    const int m = mf * 16 + quad * 4 + r;
                    const int col = nh * 256 + wave * 32 + nt * 16 + t;
                    hbuf[m][col] = (_Float16)silu_f(acc[nh][mf][nt][r] + b1v[nh][nt]);
                }

    // ---- GEMM 2 ----
    zero_acc();
    run_gemm(1);

    // ---- final layer: out = silu(acc + b2) @ W3 + b3, fp32 VALU ----
#pragma unroll
    for (int mf = 0; mf < 4; ++mf)
#pragma unroll
        for (int r = 0; r < 4; ++r) {
            float sum = 0.f;
#pragma unroll
            for (int nh = 0; nh < 2; ++nh)
#pragma unroll
                for (int nt = 0; nt < 2; ++nt)
                    sum += silu_f(acc[nh][mf][nt][r] + b2v[nh][nt]) * w3v[nh][nt];
            sum += __shfl_xor(sum, 1);
            sum += __shfl_xor(sum, 2);
            sum += __shfl_xor(sum, 4);
            sum += __shfl_xor(sum, 8);
            if (t == 0) partials[wave][mf * 16 + quad * 4 + r] = sum;
        }
    __syncthreads();
    if (tid < MTILE) {
        float o = b3[0];
#pragma unroll
        for (int w = 0; w < 8; ++w) o += partials[w][tid];
        out[(size_t)bi * MTILE + tid] = o;
    }
}

extern "C" void kernel_launch(void* const* d_in, const int* in_sizes, int n_in,
                              void* d_out, int out_size, void* d_ws, size_t ws_size,
                              hipStream_t stream) {
    const float* lat = (const float*)d_in[0];
    const float* W0  = (const float*)d_in[1];
    const float* b0  = (const float*)d_in[2];
    const float* W1  = (const float*)d_in[3];
    const float* b1  = (const float*)d_in[4];
    const float* W2  = (const float*)d_in[5];
    const float* b2  = (const float*)d_in[6];
    const float* W3  = (const float*)d_in[7];
    const float* b3  = (const float*)d_in[8];
    float* out = (float*)d_out;

    float* latw = (float*)d_ws;                               // 4 KB
    _Float16* wsplit = (_Float16*)((char*)d_ws + 4096);       // 2 MB

    prep_latw<<<2, 512, 0, stream>>>(lat, W0, b0, latw);
    prep_wsplit<<<1024, 512, 0, stream>>>(W1, W2, wsplit);
    mesh_main<<<NBLK, 512, 0, stream>>>(W0, b1, b2, W3, b3, latw, wsplit, out);
}

// Round 2
// 1761.087 us; speedup vs baseline: 4.9540x; 4.9540x over previous
//
#include <hip/hip_runtime.h>

#define H 512
#define MTILE 64
#define NBLK 8192
#define HPAD 520
#define STEPC (2.4f / 63.0f)

typedef _Float16 half8 __attribute__((ext_vector_type(8)));
typedef float floatx4 __attribute__((ext_vector_type(4)));

__device__ inline float silu_f(float x) { return x / (1.0f + __expf(-x)); }

typedef const __attribute__((address_space(1))) unsigned int* gp_t;
typedef __attribute__((address_space(3))) unsigned int* lp_t;

__device__ inline void async16(const _Float16* g, _Float16* l) {
    __builtin_amdgcn_global_load_lds((gp_t)g, (lp_t)l, 16, 0, 0);
}

// ---- prep 1: lat_part[b][j] = b0[j] + sum_d lat[b][d] * W0[d][j] ----
__global__ void prep_latw(const float* __restrict__ lat, const float* __restrict__ W0,
                          const float* __restrict__ b0, float* __restrict__ latw) {
    __shared__ float sl[H];
    const int b = blockIdx.x;
    const int j = threadIdx.x;
    sl[j] = lat[b * H + j];
    __syncthreads();
    float acc = b0[j];
#pragma unroll 8
    for (int d = 0; d < H; ++d) acc += sl[d] * W0[d * H + j];
    latw[b * H + j] = acc;
}

// ---- prep 2: split W1/W2 into fp16 hi/lo, slab-major interleaved layout ----
// slab s = (n>>8)*16 + (k>>5); within slab (16384 halves):
//   [part][kk>>3][nl][kk&7]   (part: 0=hi 1=lo, nl = n&255, kk = k&31)
// b-fragment read (fixed quad=kk>>3) is then lane-contiguous 16 B -> no LDS
// bank conflicts, and the staging image stays dense for global_load_lds.
__global__ void prep_wsplit(const float* __restrict__ W1, const float* __restrict__ W2,
                            _Float16* __restrict__ ws) {
    const int id = blockIdx.x * 512 + threadIdx.x;   // 0 .. 524287
    const int l = id >> 18;
    const int rem = id & 0x3FFFF;                    // k*512 + n
    const int k = rem >> 9, n = rem & 511;
    const float w = (l == 0 ? W1 : W2)[rem];
    const _Float16 hi = (_Float16)w;
    const _Float16 lo = (_Float16)(w - (float)hi);
    const int s = (n >> 8) * 16 + (k >> 5);
    const int nl = n & 255, kk = k & 31;
    const size_t base = (size_t)((l * 32 + s) * 2 + 0) * 8192
                      + (((kk >> 3) * 256 + nl) * 8 + (kk & 7));
    ws[base] = hi;
    ws[base + 8192] = lo;                            // part stride = 8192 halves
}

// ---- main fused kernel ----
__global__ __launch_bounds__(512, 2) void mesh_main(
    const float* __restrict__ W0, const float* __restrict__ b1,
    const float* __restrict__ b2, const float* __restrict__ W3,
    const float* __restrict__ b3, const float* __restrict__ latw,
    const _Float16* __restrict__ wsplit, float* __restrict__ out) {

    __shared__ _Float16 hbuf[MTILE][HPAD];        // 65 KB, [m][k], row pad -> 2-way only
    __shared__ _Float16 wbuf[2][2][4][256][8];    // 64 KB, [dbuf][part][kk8][n][k0]
    __shared__ float partials[8][MTILE];          // 2 KB

    const int tid = threadIdx.x;
    const int wave = tid >> 6, lane = tid & 63;
    const int quad = lane >> 4, t = lane & 15;
    const int bi = blockIdx.x;
    const int b = bi >> 12;
    const int p0 = (bi & 4095) << 6;
    const float c0 = -1.2f + (float)(p0 >> 12) * STEPC;
    const float c1 = -1.2f + (float)((p0 >> 6) & 63) * STEPC;

    // ---- layer 0: h0 = silu(lat_part + coords@W0c + b0), fp32 VALU ----
    {
        const int j = tid;
        const float lw = latw[b * H + j];
        const float w0 = W0[(H + 0) * H + j];
        const float w1 = W0[(H + 1) * H + j];
        const float w2 = W0[(H + 2) * H + j];
#pragma unroll 4
        for (int m = 0; m < MTILE; ++m) {
            const float c2 = -1.2f + (float)m * STEPC;
            const float x = lw + c0 * w0 + c1 * w1 + c2 * w2;
            hbuf[m][j] = (_Float16)silu_f(x);
        }
    }

    // per-lane column constants: col(nh,nt) = nh*256 + wave*32 + nt*16 + t
    float b1v[2][2], b2v[2][2], w3v[2][2];
#pragma unroll
    for (int nh = 0; nh < 2; ++nh)
#pragma unroll
        for (int nt = 0; nt < 2; ++nt) {
            const int col = nh * 256 + wave * 32 + nt * 16 + t;
            b1v[nh][nt] = b1[col];
            b2v[nh][nt] = b2[col];
            w3v[nh][nt] = W3[col];
        }

    // two separate acc arrays; every index on them is compile-time constant
    // (nh loops are fully unrolled) -> registers, never scratch.
    floatx4 acc0[4][2], acc1[4][2];

    auto zero4x2 = [&](floatx4 (&ac)[4][2]) {
#pragma unroll
        for (int mf = 0; mf < 4; ++mf)
#pragma unroll
            for (int nt = 0; nt < 2; ++nt) {
                ac[mf][nt][0] = 0.f; ac[mf][nt][1] = 0.f;
                ac[mf][nt][2] = 0.f; ac[mf][nt][3] = 0.f;
            }
    };

    auto stage_slab = [&](int l, int s, int buf) {
        const _Float16* src = wsplit + ((size_t)(l * 32 + s) * 16384);
        _Float16* dst = &wbuf[buf][0][0][0][0];
#pragma unroll
        for (int r = 0; r < 4; ++r)
            async16(src + r * 4096 + tid * 8, dst + r * 4096 + tid * 8);
    };

    auto compute_slab = [&](floatx4 (&ac)[4][2], int kc, int buf) {
        half8 a[4];
#pragma unroll
        for (int mf = 0; mf < 4; ++mf)
            a[mf] = *(const half8*)&hbuf[mf * 16 + t][kc * 32 + quad * 8];
#pragma unroll
        for (int nt = 0; nt < 2; ++nt) {
            const int n = wave * 32 + nt * 16 + t;
            const half8 bh = *(const half8*)&wbuf[buf][0][quad][n][0];
            const half8 bl = *(const half8*)&wbuf[buf][1][quad][n][0];
#pragma unroll
            for (int mf = 0; mf < 4; ++mf) {
                ac[mf][nt] = __builtin_amdgcn_mfma_f32_16x16x32_f16(a[mf], bh, ac[mf][nt], 0, 0, 0);
                ac[mf][nt] = __builtin_amdgcn_mfma_f32_16x16x32_f16(a[mf], bl, ac[mf][nt], 0, 0, 0);
            }
        }
    };

    auto run_gemm = [&](int l) {
        __syncthreads();              // hbuf ready; prev wbuf readers done
        stage_slab(l, 0, 0);
#pragma unroll
        for (int nh = 0; nh < 2; ++nh) {
#pragma unroll 1
            for (int kc = 0; kc < 16; ++kc) {
                const int s = nh * 16 + kc;
                __syncthreads();      // slab s resident; buf (s+1)&1 free
                if (s < 31) stage_slab(l, s + 1, (s + 1) & 1);
                compute_slab(nh ? acc1 : acc0, kc, s & 1);
            }
        }
        __syncthreads();              // all hbuf/wbuf reads retired
    };

    // ---- GEMM 1 ----
    zero4x2(acc0); zero4x2(acc1);
    run_gemm(0);
    // writeback h1 = silu(acc + b1)
#pragma unroll
    for (int nh = 0; nh < 2; ++nh) {
        floatx4 (&ac)[4][2] = nh ? acc1 : acc0;
#pragma unroll
        for (int mf = 0; mf < 4; ++mf)
#pragma unroll
            for (int nt = 0; nt < 2; ++nt)
#pragma unroll
                for (int r = 0; r < 4; ++r) {
                    const int m = mf * 16 + quad * 4 + r;
                    const int col = nh * 256 + wave * 32 + nt * 16 + t;
                    hbuf[m][col] = (_Float16)silu_f(ac[mf][nt][r] + b1v[nh][nt]);
                }
    }

    // ---- GEMM 2 ----
    zero4x2(acc0); zero4x2(acc1);
    run_gemm(1);

    // ---- final layer: out = silu(acc + b2) @ W3 + b3, fp32 VALU ----
#pragma unroll
    for (int mf = 0; mf < 4; ++mf)
#pragma unroll
        for (int r = 0; r < 4; ++r) {
            float sum = 0.f;
#pragma unroll
            for (int nh = 0; nh < 2; ++nh) {
                floatx4 (&ac)[4][2] = nh ? acc1 : acc0;
#pragma unroll
                for (int nt = 0; nt < 2; ++nt)
                    sum += silu_f(ac[mf][nt][r] + b2v[nh][nt]) * w3v[nh][nt];
            }
            sum += __shfl_xor(sum, 1);
            sum += __shfl_xor(sum, 2);
            sum += __shfl_xor(sum, 4);
            sum += __shfl_xor(sum, 8);
            if (t == 0) partials[wave][mf * 16 + quad * 4 + r] = sum;
        }
    __syncthreads();
    if (tid < MTILE) {
        float o = b3[0];
#pragma unroll
        for (int w = 0; w < 8; ++w) o += partials[w][tid];
        out[(size_t)bi * MTILE + tid] = o;
    }
}

extern "C" void kernel_launch(void* const* d_in, const int* in_sizes, int n_in,
                              void* d_out, int out_size, void* d_ws, size_t ws_size,
                              hipStream_t stream) {
    const float* lat = (const float*)d_in[0];
    const float* W0  = (const float*)d_in[1];
    const float* b0  = (const float*)d_in[2];
    const float* W1  = (const float*)d_in[3];
    const float* b1  = (const float*)d_in[4];
    const float* W2  = (const float*)d_in[5];
    const float* b2  = (const float*)d_in[6];
    const float* W3  = (const float*)d_in[7];
    const float* b3  = (const float*)d_in[8];
    float* out = (float*)d_out;

    float* latw = (float*)d_ws;                               // 4 KB
    _Float16* wsplit = (_Float16*)((char*)d_ws + 4096);       // 2 MB

    prep_latw<<<2, 512, 0, stream>>>(lat, W0, b0, latw);
    prep_wsplit<<<1024, 512, 0, stream>>>(W1, W2, wsplit);
    mesh_main<<<NBLK, 512, 0, stream>>>(W0, b1, b2, W3, b3, latw, wsplit, out);
}

// Round 3
// 1207.815 us; speedup vs baseline: 7.2233x; 1.4581x over previous
//
#include <hip/hip_runtime.h>

#define H 512
#define MTILE 128
#define NBLK 4096
#define HPAD 520
#define STEPC (2.4f / 63.0f)

typedef _Float16 half8 __attribute__((ext_vector_type(8)));
typedef float floatx4 __attribute__((ext_vector_type(4)));

__device__ inline float silu_f(float x) { return x / (1.0f + __expf(-x)); }

// ---- prep 1: lat_part[b][j] = b0[j] + sum_d lat[b][d] * W0[d][j] ----
__global__ void prep_latw(const float* __restrict__ lat, const float* __restrict__ W0,
                          const float* __restrict__ b0, float* __restrict__ latw) {
    __shared__ float sl[H];
    const int b = blockIdx.x;
    const int j = threadIdx.x;
    sl[j] = lat[b * H + j];
    __syncthreads();
    float acc = b0[j];
#pragma unroll 8
    for (int d = 0; d < H; ++d) acc += sl[d] * W0[d * H + j];
    latw[b * H + j] = acc;
}

// ---- prep 2: split W1/W2 into fp16 hi/lo, fragment-major layout for direct
// L2->register B loads.  idx = ((((l*16+kc)*2+p)*4+q)*512 + n)*8 + k0
// (kc=k>>5, q=(k>>3)&3, k0=k&7).  A wave's 16-byte fragment load for fixed
// (l,kc,p,nt) is then contiguous across lanes within a quad.
__global__ void prep_wsplit(const float* __restrict__ W1, const float* __restrict__ W2,
                            _Float16* __restrict__ ws) {
    const int id = blockIdx.x * 512 + threadIdx.x;   // 0 .. 524287
    const int l = id >> 18;
    const int rem = id & 0x3FFFF;                    // k*512 + n
    const int k = rem >> 9, n = rem & 511;
    const float w = (l == 0 ? W1 : W2)[rem];
    const _Float16 hi = (_Float16)w;
    const _Float16 lo = (_Float16)(w - (float)hi);
    const int kc = k >> 5, q = (k >> 3) & 3, k0 = k & 7;
    const size_t base = ((size_t)(((l * 16 + kc) * 2 + 0) * 4 + q) * 512 + n) * 8 + k0;
    ws[base] = hi;
    ws[base + 16384] = lo;                           // part stride = 4*512*8
}

// ---- main fused kernel: barrier-free K-loop, B streamed from L2 ----
__global__ __launch_bounds__(512, 2) void mesh_main(
    const float* __restrict__ W0, const float* __restrict__ b1,
    const float* __restrict__ b2, const float* __restrict__ W3,
    const float* __restrict__ b3, const float* __restrict__ latw,
    const _Float16* __restrict__ wsB, float* __restrict__ out) {

    __shared__ _Float16 hbuf[MTILE][HPAD];        // 130 KB, [m][k]
    __shared__ float partials[8][MTILE];          // 4 KB

    const int tid = threadIdx.x;
    const int wave = tid >> 6, lane = tid & 63;
    const int q = lane >> 4, t = lane & 15;
    const int bi = blockIdx.x;
    const int b = bi >> 11;
    const int p0 = (bi & 2047) << 7;              // 128 rows per block
    const float c0 = -1.2f + (float)(p0 >> 12) * STEPC;
    const float c1b = -1.2f + (float)((p0 >> 6) & 63) * STEPC;

    // ---- layer 0: h0 = silu(lat_part + coords@W0c + b0), fp32 VALU ----
    {
        const int j = tid;
        const float w1c = W0[(H + 1) * H + j];
        const float w2c = W0[(H + 2) * H + j];
        const float lw0 = latw[b * H + j] + c0 * W0[(H + 0) * H + j];
#pragma unroll 4
        for (int m = 0; m < MTILE; ++m) {
            const float c1v = c1b + (float)(m >> 6) * STEPC;
            const float c2v = -1.2f + (float)(m & 63) * STEPC;
            const float x = lw0 + c1v * w1c + c2v * w2c;
            hbuf[m][j] = (_Float16)silu_f(x);
        }
    }

    // column owned by this lane for fragment nt: col = nt*128 + wave*16 + t
    float b1v[4], b2v[4], w3v[4];
#pragma unroll
    for (int nt = 0; nt < 4; ++nt) {
        const int col = nt * 128 + wave * 16 + t;
        b1v[nt] = b1[col];
        b2v[nt] = b2[col];
        w3v[nt] = W3[col];
    }

    // per-lane base into the B image (quad + lane column part)
    const _Float16* wsl = wsB + ((q * 512) + wave * 16 + t) * 8;

    floatx4 acc[8][4];     // [mf][nt] — all indices compile-time constant

    auto zero_acc = [&]() {
#pragma unroll
        for (int mf = 0; mf < 8; ++mf)
#pragma unroll
            for (int nt = 0; nt < 4; ++nt) {
                acc[mf][nt][0] = 0.f; acc[mf][nt][1] = 0.f;
                acc[mf][nt][2] = 0.f; acc[mf][nt][3] = 0.f;
            }
    };

    auto loadB = [&](int l, int kc, half8 (&bh)[4], half8 (&bl)[4]) {
        const _Float16* p = wsl + (size_t)(l * 16 + kc) * 32768;
#pragma unroll
        for (int nt = 0; nt < 4; ++nt) {
            bh[nt] = *(const half8*)(p + nt * 1024);
            bl[nt] = *(const half8*)(p + 16384 + nt * 1024);
        }
    };

    auto compute = [&](int kc, half8 (&bh)[4], half8 (&bl)[4]) {
        half8 a[8];
#pragma unroll
        for (int mf = 0; mf < 8; ++mf)
            a[mf] = *(const half8*)&hbuf[mf * 16 + t][kc * 32 + q * 8];
#pragma unroll
        for (int nt = 0; nt < 4; ++nt)
#pragma unroll
            for (int mf = 0; mf < 8; ++mf) {
                acc[mf][nt] = __builtin_amdgcn_mfma_f32_16x16x32_f16(a[mf], bh[nt], acc[mf][nt], 0, 0, 0);
                acc[mf][nt] = __builtin_amdgcn_mfma_f32_16x16x32_f16(a[mf], bl[nt], acc[mf][nt], 0, 0, 0);
            }
    };

    auto run_gemm = [&](int l) {
        half8 BH0[4], BL0[4], BH1[4], BL1[4];
        loadB(l, 0, BH0, BL0);
#pragma unroll 1
        for (int kc = 0; kc < 16; kc += 2) {
            loadB(l, kc + 1, BH1, BL1);
            compute(kc, BH0, BL0);
            loadB(l, (kc + 2 < 16) ? kc + 2 : 14, BH0, BL0);  // last reload harmless
            compute(kc + 1, BH1, BL1);
        }
    };

    // ---- GEMM 1 ----
    zero_acc();
    __syncthreads();             // hbuf (h0) ready
    run_gemm(0);
    __syncthreads();             // all waves done reading h0
    // writeback h1 = silu(acc + b1)
#pragma unroll
    for (int mf = 0; mf < 8; ++mf)
#pragma unroll
        for (int nt = 0; nt < 4; ++nt)
#pragma unroll
            for (int r = 0; r < 4; ++r) {
                const int m = mf * 16 + q * 4 + r;
                const int col = nt * 128 + wave * 16 + t;
                hbuf[m][col] = (_Float16)silu_f(acc[mf][nt][r] + b1v[nt]);
            }

    // ---- GEMM 2 ----
    zero_acc();
    __syncthreads();             // h1 ready
    run_gemm(1);

    // ---- final layer: out = silu(acc + b2) @ W3 + b3, fp32 VALU ----
#pragma unroll
    for (int mf = 0; mf < 8; ++mf)
#pragma unroll
        for (int r = 0; r < 4; ++r) {
            float sum = 0.f;
#pragma unroll
            for (int nt = 0; nt < 4; ++nt)
                sum += silu_f(acc[mf][nt][r] + b2v[nt]) * w3v[nt];
            sum += __shfl_xor(sum, 1);
            sum += __shfl_xor(sum, 2);
            sum += __shfl_xor(sum, 4);
            sum += __shfl_xor(sum, 8);
            if (t == 0) partials[wave][mf * 16 + q * 4 + r] = sum;
        }
    __syncthreads();
    if (tid < MTILE) {
        float o = b3[0];
#pragma unroll
        for (int w = 0; w < 8; ++w) o += partials[w][tid];
        out[(size_t)bi * MTILE + tid] = o;
    }
}

extern "C" void kernel_launch(void* const* d_in, const int* in_sizes, int n_in,
                              void* d_out, int out_size, void* d_ws, size_t ws_size,
                              hipStream_t stream) {
    const float* lat = (const float*)d_in[0];
    const float* W0  = (const float*)d_in[1];
    const float* b0  = (const float*)d_in[2];
    const float* W1  = (const float*)d_in[3];
    const float* b1  = (const float*)d_in[4];
    const float* W2  = (const float*)d_in[5];
    const float* b2  = (const float*)d_in[6];
    const float* W3  = (const float*)d_in[7];
    const float* b3  = (const float*)d_in[8];
    float* out = (float*)d_out;

    float* latw = (float*)d_ws;                               // 4 KB
    _Float16* wsB = (_Float16*)((char*)d_ws + 4096);          // 2 MB

    prep_latw<<<2, 512, 0, stream>>>(lat, W0, b0, latw);
    prep_wsplit<<<1024, 512, 0, stream>>>(W1, W2, wsB);
    mesh_main<<<NBLK, 512, 0, stream>>>(W0, b1, b2, W3, b3, latw, wsB, out);
}

// Round 4
// 774.251 us; speedup vs baseline: 11.2682x; 1.5600x over previous
//
#include <hip/hip_runtime.h>

#define H 512
#define MTILE 64
#define NBLK 8192
#define HPAD 520
#define STEPC (2.4f / 63.0f)

typedef _Float16 half8 __attribute__((ext_vector_type(8)));
typedef float floatx4 __attribute__((ext_vector_type(4)));

__device__ inline float silu_f(float x) { return x / (1.0f + __expf(-x)); }

// ---- prep 1: lat_part[b][j] = b0[j] + sum_d lat[b][d] * W0[d][j] ----
__global__ void prep_latw(const float* __restrict__ lat, const float* __restrict__ W0,
                          const float* __restrict__ b0, float* __restrict__ latw) {
    __shared__ float sl[H];
    const int b = blockIdx.x;
    const int j = threadIdx.x;
    sl[j] = lat[b * H + j];
    __syncthreads();
    float acc = b0[j];
#pragma unroll 8
    for (int d = 0; d < H; ++d) acc += sl[d] * W0[d * H + j];
    latw[b * H + j] = acc;
}

// ---- prep 2: W1/W2 -> fp16, fragment-major for direct L2->reg B loads ----
// kc=k>>5, q=(k>>3)&3, k0=k&7;  idx = (((l*16+kc)*4+q)*512 + n)*8 + k0
// A quad's 16-byte fragment load is contiguous across its 16 lanes.
__global__ void prep_w16(const float* __restrict__ W1, const float* __restrict__ W2,
                         _Float16* __restrict__ ws) {
    const int id = blockIdx.x * 512 + threadIdx.x;   // 0 .. 524287
    const int l = id >> 18;
    const int rem = id & 0x3FFFF;                    // k*512 + n
    const int k = rem >> 9, n = rem & 511;
    const float w = (l == 0 ? W1 : W2)[rem];
    const int kc = k >> 5, q = (k >> 3) & 3, k0 = k & 7;
    ws[((size_t)((l * 16 + kc) * 4 + q) * 512 + n) * 8 + k0] = (_Float16)w;
}

// ---- main fused kernel: barrier-free K-loop, B from L2, 2 blocks/CU ----
__global__ __launch_bounds__(512, 4) void mesh_main(
    const float* __restrict__ W0, const float* __restrict__ b1,
    const float* __restrict__ b2, const float* __restrict__ W3,
    const float* __restrict__ b3, const float* __restrict__ latw,
    const _Float16* __restrict__ wsB, float* __restrict__ out) {

    __shared__ _Float16 hbuf[MTILE][HPAD];        // 66.5 KB
    __shared__ float partials[8][MTILE];          // 2 KB  -> 68.6 KB total

    const int tid = threadIdx.x;
    const int wave = tid >> 6, lane = tid & 63;
    const int q = lane >> 4, t = lane & 15;
    const int bi = blockIdx.x;
    const int b = bi >> 12;
    const int p0 = (bi & 4095) << 6;              // 64 rows per block (fixed x,y)
    const float c0 = -1.2f + (float)(p0 >> 12) * STEPC;
    const float c1 = -1.2f + (float)((p0 >> 6) & 63) * STEPC;

    // ---- layer 0: h0 = silu(lat_part + coords@W0c + b0), fp32 VALU ----
    {
        const int j = tid;
        const float w2c = W0[(H + 2) * H + j];
        const float lw = latw[b * H + j]
                       + c0 * W0[(H + 0) * H + j]
                       + c1 * W0[(H + 1) * H + j];
#pragma unroll 4
        for (int m = 0; m < MTILE; ++m) {
            const float c2v = -1.2f + (float)m * STEPC;
            hbuf[m][j] = (_Float16)silu_f(lw + c2v * w2c);
        }
    }

    // per-lane base into the B image (quad + lane column part)
    const _Float16* wsl = wsB + ((size_t)q * 512 + wave * 16 + t) * 8;

    floatx4 acc[4][4];     // [mf][nt] — all indices compile-time constant

    auto zero_acc = [&]() {
#pragma unroll
        for (int mf = 0; mf < 4; ++mf)
#pragma unroll
            for (int nt = 0; nt < 4; ++nt) {
                acc[mf][nt][0] = 0.f; acc[mf][nt][1] = 0.f;
                acc[mf][nt][2] = 0.f; acc[mf][nt][3] = 0.f;
            }
    };

    auto loadB = [&](int l, int kc, half8 (&bf)[4]) {
        const _Float16* p = wsl + (size_t)(l * 16 + kc) * 16384;
#pragma unroll
        for (int nt = 0; nt < 4; ++nt)
            bf[nt] = *(const half8*)(p + nt * 1024);   // nt*128 cols * 8
    };

    auto compute = [&](int kc, half8 (&bf)[4]) {
        half8 a[4];
#pragma unroll
        for (int mf = 0; mf < 4; ++mf)
            a[mf] = *(const half8*)&hbuf[mf * 16 + t][kc * 32 + q * 8];
#pragma unroll
        for (int nt = 0; nt < 4; ++nt)
#pragma unroll
            for (int mf = 0; mf < 4; ++mf)
                acc[mf][nt] = __builtin_amdgcn_mfma_f32_16x16x32_f16(a[mf], bf[nt], acc[mf][nt], 0, 0, 0);
    };

    auto run_gemm = [&](int l) {
        half8 B0[4], B1[4];
        loadB(l, 0, B0);
#pragma unroll 1
        for (int kc = 0; kc < 16; kc += 2) {
            loadB(l, kc + 1, B1);
            compute(kc, B0);
            loadB(l, (kc + 2) & 15, B0);    // wraps to 0 on last iter: harmless
            compute(kc + 1, B1);
        }
    };

    // ---- GEMM 1 ----
    zero_acc();
    __syncthreads();             // h0 ready
    run_gemm(0);
    __syncthreads();             // all waves done reading h0
    // writeback h1 = silu(acc + b1)  (b1 reloaded here, not held live)
    {
        float b1v[4];
#pragma unroll
        for (int nt = 0; nt < 4; ++nt) b1v[nt] = b1[nt * 128 + wave * 16 + t];
#pragma unroll
        for (int mf = 0; mf < 4; ++mf)
#pragma unroll
            for (int nt = 0; nt < 4; ++nt)
#pragma unroll
                for (int r = 0; r < 4; ++r) {
                    const int m = mf * 16 + q * 4 + r;
                    const int col = nt * 128 + wave * 16 + t;
                    hbuf[m][col] = (_Float16)silu_f(acc[mf][nt][r] + b1v[nt]);
                }
    }

    // ---- GEMM 2 ----
    zero_acc();
    __syncthreads();             // h1 ready
    run_gemm(1);

    // ---- final layer: out = silu(acc + b2) @ W3 + b3, fp32 VALU ----
    {
        float b2v[4], w3v[4];
#pragma unroll
        for (int nt = 0; nt < 4; ++nt) {
            const int col = nt * 128 + wave * 16 + t;
            b2v[nt] = b2[col];
            w3v[nt] = W3[col];
        }
#pragma unroll
        for (int mf = 0; mf < 4; ++mf)
#pragma unroll
            for (int r = 0; r < 4; ++r) {
                float sum = 0.f;
#pragma unroll
                for (int nt = 0; nt < 4; ++nt)
                    sum += silu_f(acc[mf][nt][r] + b2v[nt]) * w3v[nt];
                sum += __shfl_xor(sum, 1);
                sum += __shfl_xor(sum, 2);
                sum += __shfl_xor(sum, 4);
                sum += __shfl_xor(sum, 8);
                if (t == 0) partials[wave][mf * 16 + q * 4 + r] = sum;
            }
    }
    __syncthreads();
    if (tid < MTILE) {
        float o = b3[0];
#pragma unroll
        for (int w = 0; w < 8; ++w) o += partials[w][tid];
        out[(size_t)bi * MTILE + tid] = o;
    }
}

extern "C" void kernel_launch(void* const* d_in, const int* in_sizes, int n_in,
                              void* d_out, int out_size, void* d_ws, size_t ws_size,
                              hipStream_t stream) {
    const float* lat = (const float*)d_in[0];
    const float* W0  = (const float*)d_in[1];
    const float* b0  = (const float*)d_in[2];
    const float* W1  = (const float*)d_in[3];
    const float* b1  = (const float*)d_in[4];
    const float* W2  = (const float*)d_in[5];
    const float* b2  = (const float*)d_in[6];
    const float* W3  = (const float*)d_in[7];
    const float* b3  = (const float*)d_in[8];
    float* out = (float*)d_out;

    float* latw = (float*)d_ws;                               // 4 KB
    _Float16* wsB = (_Float16*)((char*)d_ws + 4096);          // 1 MB

    prep_latw<<<2, 512, 0, stream>>>(lat, W0, b0, latw);
    prep_w16<<<1024, 512, 0, stream>>>(W1, W2, wsB);
    mesh_main<<<NBLK, 512, 0, stream>>>(W0, b1, b2, W3, b3, latw, wsB, out);
}

// Round 5
// 760.066 us; speedup vs baseline: 11.4785x; 1.0187x over previous
//
#include <hip/hip_runtime.h>

#define H 512
#define MTILE 64
#define NBLK 8192
#define HPAD 520
#define STEPC (2.4f / 63.0f)

typedef _Float16 half8 __attribute__((ext_vector_type(8)));
typedef float floatx4 __attribute__((ext_vector_type(4)));

// fast silu: native exp + native rcp (v_exp_f32 / v_rcp_f32), no fp32 div seq.
// rcp rel-err ~1e-7 -- negligible vs fp16-h rounding (absmax budget 2.9e-3).
__device__ inline float silu_f(float x) {
    return __fdividef(x, 1.0f + __expf(-x));
}

// ---- prep 1: lat_part[b][j] = b0[j] + sum_d lat[b][d] * W0[d][j] ----
__global__ void prep_latw(const float* __restrict__ lat, const float* __restrict__ W0,
                          const float* __restrict__ b0, float* __restrict__ latw) {
    __shared__ float sl[H];
    const int b = blockIdx.x;
    const int j = threadIdx.x;
    sl[j] = lat[b * H + j];
    __syncthreads();
    float acc = b0[j];
#pragma unroll 8
    for (int d = 0; d < H; ++d) acc += sl[d] * W0[d * H + j];
    latw[b * H + j] = acc;
}

// ---- prep 2: W1/W2 -> fp16, fragment-major for direct L2->reg B loads ----
// kc=k>>5, q=(k>>3)&3, k0=k&7;  idx = (((l*16+kc)*4+q)*512 + n)*8 + k0
__global__ void prep_w16(const float* __restrict__ W1, const float* __restrict__ W2,
                         _Float16* __restrict__ ws) {
    const int id = blockIdx.x * 512 + threadIdx.x;   // 0 .. 524287
    const int l = id >> 18;
    const int rem = id & 0x3FFFF;                    // k*512 + n
    const int k = rem >> 9, n = rem & 511;
    const float w = (l == 0 ? W1 : W2)[rem];
    const int kc = k >> 5, q = (k >> 3) & 3, k0 = k & 7;
    ws[((size_t)((l * 16 + kc) * 4 + q) * 512 + n) * 8 + k0] = (_Float16)w;
}

// ---- main fused kernel: barrier-free K-loop, B from L2, 2 blocks/CU ----
__global__ __launch_bounds__(512, 4) void mesh_main(
    const float* __restrict__ W0, const float* __restrict__ b1,
    const float* __restrict__ b2, const float* __restrict__ W3,
    const float* __restrict__ b3, const float* __restrict__ latw,
    const _Float16* __restrict__ wsB, float* __restrict__ out) {

    __shared__ _Float16 hbuf[MTILE][HPAD];        // 66.5 KB
    __shared__ float partials[8][MTILE];          // 2 KB  -> 68.6 KB total

    const int tid = threadIdx.x;
    const int wave = tid >> 6, lane = tid & 63;
    const int q = lane >> 4, t = lane & 15;
    const int bi = blockIdx.x;
    const int b = bi >> 12;
    const int p0 = (bi & 4095) << 6;              // 64 rows per block (fixed x,y)
    const float c0 = -1.2f + (float)(p0 >> 12) * STEPC;
    const float c1 = -1.2f + (float)((p0 >> 6) & 63) * STEPC;

    // ---- layer 0: h0 = silu(lat_part + coords@W0c + b0), fp32 VALU ----
    {
        const int j = tid;
        const float w2c = W0[(H + 2) * H + j];
        const float lw = latw[b * H + j]
                       + c0 * W0[(H + 0) * H + j]
                       + c1 * W0[(H + 1) * H + j];
#pragma unroll 4
        for (int m = 0; m < MTILE; ++m) {
            const float c2v = -1.2f + (float)m * STEPC;
            hbuf[m][j] = (_Float16)silu_f(lw + c2v * w2c);
        }
    }

    // per-lane base into the B image (quad + lane column part)
    const _Float16* wsl = wsB + ((size_t)q * 512 + wave * 16 + t) * 8;

    floatx4 acc[4][4];     // [mf][nt] — all indices compile-time constant

    auto zero_acc = [&]() {
#pragma unroll
        for (int mf = 0; mf < 4; ++mf)
#pragma unroll
            for (int nt = 0; nt < 4; ++nt) {
                acc[mf][nt][0] = 0.f; acc[mf][nt][1] = 0.f;
                acc[mf][nt][2] = 0.f; acc[mf][nt][3] = 0.f;
            }
    };

    auto loadB = [&](int l, int kc, half8 (&bf)[4]) {
        const _Float16* p = wsl + (size_t)(l * 16 + kc) * 16384;
#pragma unroll
        for (int nt = 0; nt < 4; ++nt)
            bf[nt] = *(const half8*)(p + nt * 1024);   // nt*128 cols * 8
    };

    auto compute = [&](int kc, half8 (&bf)[4]) {
        half8 a[4];
#pragma unroll
        for (int mf = 0; mf < 4; ++mf)
            a[mf] = *(const half8*)&hbuf[mf * 16 + t][kc * 32 + q * 8];
#pragma unroll
        for (int nt = 0; nt < 4; ++nt)
#pragma unroll
            for (int mf = 0; mf < 4; ++mf)
                acc[mf][nt] = __builtin_amdgcn_mfma_f32_16x16x32_f16(a[mf], bf[nt], acc[mf][nt], 0, 0, 0);
    };

    auto run_gemm = [&](int l) {
        half8 B0[4], B1[4];
        loadB(l, 0, B0);
#pragma unroll 1
        for (int kc = 0; kc < 16; kc += 2) {
            loadB(l, kc + 1, B1);
            compute(kc, B0);
            loadB(l, (kc + 2) & 15, B0);    // wraps to 0 on last iter: harmless
            compute(kc + 1, B1);
        }
    };

    // ---- GEMM 1 ----
    zero_acc();
    __syncthreads();             // h0 ready
    run_gemm(0);
    __syncthreads();             // all waves done reading h0
    // writeback h1 = silu(acc + b1)  (b1 reloaded here, not held live)
    {
        float b1v[4];
#pragma unroll
        for (int nt = 0; nt < 4; ++nt) b1v[nt] = b1[nt * 128 + wave * 16 + t];
#pragma unroll
        for (int mf = 0; mf < 4; ++mf)
#pragma unroll
            for (int nt = 0; nt < 4; ++nt)
#pragma unroll
                for (int r = 0; r < 4; ++r) {
                    const int m = mf * 16 + q * 4 + r;
                    const int col = nt * 128 + wave * 16 + t;
                    hbuf[m][col] = (_Float16)silu_f(acc[mf][nt][r] + b1v[nt]);
                }
    }

    // ---- GEMM 2 ----
    zero_acc();
    __syncthreads();             // h1 ready
    run_gemm(1);

    // ---- final layer: out = silu(acc + b2) @ W3 + b3, fp32 VALU ----
    {
        float b2v[4], w3v[4];
#pragma unroll
        for (int nt = 0; nt < 4; ++nt) {
            const int col = nt * 128 + wave * 16 + t;
            b2v[nt] = b2[col];
            w3v[nt] = W3[col];
        }
#pragma unroll
        for (int mf = 0; mf < 4; ++mf)
#pragma unroll
            for (int r = 0; r < 4; ++r) {
                float sum = 0.f;
#pragma unroll
                for (int nt = 0; nt < 4; ++nt)
                    sum += silu_f(acc[mf][nt][r] + b2v[nt]) * w3v[nt];
                sum += __shfl_xor(sum, 1);
                sum += __shfl_xor(sum, 2);
                sum += __shfl_xor(sum, 4);
                sum += __shfl_xor(sum, 8);
                if (t == 0) partials[wave][mf * 16 + q * 4 + r] = sum;
            }
    }
    __syncthreads();
    if (tid < MTILE) {
        float o = b3[0];
#pragma unroll
        for (int w = 0; w < 8; ++w) o += partials[w][tid];
        out[(size_t)bi * MTILE + tid] = o;
    }
}

extern "C" void kernel_launch(void* const* d_in, const int* in_sizes, int n_in,
                              void* d_out, int out_size, void* d_ws, size_t ws_size,
                              hipStream_t stream) {
    const float* lat = (const float*)d_in[0];
    const float* W0  = (const float*)d_in[1];
    const float* b0  = (const float*)d_in[2];
    const float* W1  = (const float*)d_in[3];
    const float* b1  = (const float*)d_in[4];
    const float* W2  = (const float*)d_in[5];
    const float* b2  = (const float*)d_in[6];
    const float* W3  = (const float*)d_in[7];
    const float* b3  = (const float*)d_in[8];
    float* out = (float*)d_out;

    float* latw = (float*)d_ws;                               // 4 KB
    _Float16* wsB = (_Float16*)((char*)d_ws + 4096);          // 1 MB

    prep_latw<<<2, 512, 0, stream>>>(lat, W0, b0, latw);
    prep_w16<<<1024, 512, 0, stream>>>(W1, W2, wsB);
    mesh_main<<<NBLK, 512, 0, stream>>>(W0, b1, b2, W3, b3, latw, wsB, out);
}